// Round 13
// baseline (74153.467 us; speedup 1.0000x reference)
//
#include <hip/hip_runtime.h>
#include <math.h>

#define T_STEPS 8192
#define I_DIM   64
#define H_DIM   2048
#define O_DIM   128
#define NBLK    256     // one block per CU; each owns 8 h-indices (32 gate rows)
#define NTHR    512     // 8 waves
#define NCNT    8       // readiness counters, one 64B line each

typedef float v4f __attribute__((ext_vector_type(4)));

// ws layout (dwords): Hbits[2][2048] | counters at 4096 + i*16 (64B stride)
#define CNT_BASE 4096

__device__ __forceinline__ float sigmoid_f(float x) {
    return 1.0f / (1.0f + __expf(-x));
}
__device__ __forceinline__ float tanh_fast(float x) {
    // 2*sigmoid(2x)-1; saturates correctly for |x| large
    return 2.0f / (1.0f + __expf(-2.0f * x)) - 1.0f;
}

// DPP wave64 sum (VALU pipe, not LDS pipe). Lane 63 ends with the full sum.
template <int CTRL>
__device__ __forceinline__ float dpp_add(float v) {
    int s = __builtin_amdgcn_update_dpp(0, __builtin_bit_cast(int, v),
                                        CTRL, 0xF, 0xF, true);
    return v + __builtin_bit_cast(float, s);
}
__device__ __forceinline__ float wave_sum64_lane63(float v) {
    v = dpp_add<0x111>(v);  // row_shr:1
    v = dpp_add<0x112>(v);  // row_shr:2
    v = dpp_add<0x114>(v);  // row_shr:4
    v = dpp_add<0x118>(v);  // row_shr:8
    v = dpp_add<0x142>(v);  // row_bcast:15
    v = dpp_add<0x143>(v);  // row_bcast:31 -> lane63 = sum(0..63)
    return v;
}

__global__ void init_ws_kernel(unsigned int* Hbits) {
    int tid = blockIdx.x * blockDim.x + threadIdx.x;
    if (tid < 2 * H_DIM) Hbits[tid] = 0u;              // slot0 = h_0 = 0; slot1 don't-care
    if (tid < NCNT)      Hbits[CNT_BASE + tid * 16] = 0u;
}

// Persistent LSTM recurrence — round-9 compute core (proven best) with
// counter-based readiness instead of data-polling.
//   Producers: publish h (ONE coalesced 32B agent store, wave0 lanes<8 — the
//   proven pattern; scattering = round-4/5 8x regression), then lane 0 does
//   release-fence (s_waitcnt vmcnt(0); cheap — write-through stores, no cache
//   maintenance; the expensive op was round-2's ACQUIRE buffer_inv) and
//   atomicAdd(counter[cu&7]). Counters are monotonic: target 32*t, no resets.
//   Consumers: poll ONLY the 8 counter lines (one coalesced 8-line request
//   per wave per pass ~ 2K chip-wide vs 32K for data-polling: the round-9
//   LLC congestion mechanism), then ONE-SHOT burst read of h.
// NSLOT=2 safe: counter>=32*(t+1) => every CU staged h_t.
// Wave w: gate q = w>>1, joff = (w&1)*4; rows = q*2048 + cu*8 + joff + i
// Dot k-mapping: lane l covers k = m*256 + l*4 + j -> one ds_read_b128 per m.
__global__ __launch_bounds__(NTHR, 2) void lstm_persistent(
    const float* __restrict__ x,     // [T, 64]
    const float* __restrict__ Wih,   // [8192, 64]
    const float* __restrict__ Whh,   // [8192, 2048]
    const float* __restrict__ bih,   // [8192]
    const float* __restrict__ bhh,   // [8192]
    unsigned int* __restrict__ Hbits)// ws: [2][2048] h + 8 padded counters
{
    const int cu   = blockIdx.x;
    const int tid  = threadIdx.x;
    const int w    = tid >> 6;
    const int lane = tid & 63;

    __shared__ float hbuf[H_DIM];   // 8 KB, hbuf[k] = h[k]
    __shared__ float xbuf[I_DIM];
    __shared__ float gbuf[32];      // gbuf[g*8 + j] = gate-g preact of h-sub j

    const int q    = w >> 1;
    const int joff = (w & 1) * 4;
    const int row0 = q * H_DIM + cu * 8 + joff;

    unsigned int* Cnt   = Hbits + CNT_BASE;
    unsigned int* myCnt = Cnt + (cu & 7) * 16;
    const unsigned int* pollCnt = Cnt + (lane & 7) * 16;

    // ---- one-time: W_hh fragment into registers ----
    // wreg[i][m] = W[row0+i][m*256 + lane*4 .. +3]   (coalesced 16B loads)
    v4f wreg[4][8];
#pragma unroll
    for (int i = 0; i < 4; i++) {
        const float* p = Whh + (size_t)(row0 + i) * H_DIM + lane * 4;
#pragma unroll
        for (int m = 0; m < 8; m++)
            wreg[i][m] = *(const v4f*)(p + m * 256);
    }
    // x-part: lane handles row (row0 + (lane>>4)), k-range (lane&15)*4 .. +4
    float xw[4];
    {
        const int xr = row0 + (lane >> 4);
        const float* p = Wih + (size_t)xr * I_DIM + (lane & 15) * 4;
#pragma unroll
        for (int m = 0; m < 4; m++) xw[m] = p[m];
    }
    // biases: every wave keeps them (elementwise phase is replicated per wave —
    // keeps waves busy through the publish window; wave0-only tail congested
    // the LLC in rounds 10/11)
    float bias[4] = {0.f, 0.f, 0.f, 0.f};
    if (lane < 8) {
#pragma unroll
        for (int g = 0; g < 4; g++) {
            int r = g * H_DIM + cu * 8 + lane;
            bias[g] = bih[r] + bhh[r];
        }
    }
    float cstate = 0.0f;   // replicated in lanes 0..7 of every wave

    for (int t = 0; t < T_STEPS; t++) {
        const int slot_r = t & 1;
        const int slot_w = (t + 1) & 1;
        const unsigned int target = 32u * (unsigned int)t;

        // hoist the independent x load above the spin
        float xv_own = (tid < I_DIM) ? x[(size_t)t * I_DIM + tid] : 0.0f;

        // ---- 1a. poll the 8 counter lines until all CUs published h_t ----
        if (target) {
            for (;;) {
                unsigned int c = __hip_atomic_load(pollCnt, __ATOMIC_RELAXED,
                                                   __HIP_MEMORY_SCOPE_AGENT);
                if (__all((int)(c >= target))) break;
                __builtin_amdgcn_s_sleep(1);
            }
        }
        // ---- 1b. one-shot burst read of h_t (round-9 strided mapping), stage ----
        {
            const unsigned int* Hr = Hbits + slot_r * H_DIM;
            unsigned int u0, u1, u2, u3;
            u0 = __hip_atomic_load(Hr + tid,            __ATOMIC_RELAXED, __HIP_MEMORY_SCOPE_AGENT);
            u1 = __hip_atomic_load(Hr + tid + 1 * NTHR, __ATOMIC_RELAXED, __HIP_MEMORY_SCOPE_AGENT);
            u2 = __hip_atomic_load(Hr + tid + 2 * NTHR, __ATOMIC_RELAXED, __HIP_MEMORY_SCOPE_AGENT);
            u3 = __hip_atomic_load(Hr + tid + 3 * NTHR, __ATOMIC_RELAXED, __HIP_MEMORY_SCOPE_AGENT);
            hbuf[tid]            = __uint_as_float(u0);
            hbuf[tid + 1 * NTHR] = __uint_as_float(u1);
            hbuf[tid + 2 * NTHR] = __uint_as_float(u2);
            hbuf[tid + 3 * NTHR] = __uint_as_float(u3);
            if (tid < I_DIM) xbuf[tid] = xv_own;
        }
        __syncthreads();   // barrier 1: hbuf/xbuf ready

        // ---- 2. dot products: 4 rows per wave, 8 x (ds_read_b128 + packed FMA) ----
        v4f av0 = {0.f,0.f,0.f,0.f}, av1 = {0.f,0.f,0.f,0.f};
        v4f av2 = {0.f,0.f,0.f,0.f}, av3 = {0.f,0.f,0.f,0.f};
#pragma unroll
        for (int m = 0; m < 8; m++) {
            v4f hv = *(const v4f*)&hbuf[m * 256 + lane * 4];
            av0 += wreg[0][m] * hv;
            av1 += wreg[1][m] * hv;
            av2 += wreg[2][m] * hv;
            av3 += wreg[3][m] * hv;
        }
        float acc0 = (av0[0] + av0[1]) + (av0[2] + av0[3]);
        float acc1 = (av1[0] + av1[1]) + (av1[2] + av1[3]);
        float acc2 = (av2[0] + av2[1]) + (av2[2] + av2[3]);
        float acc3 = (av3[0] + av3[1]) + (av3[2] + av3[3]);
        {   // fold in W_ih * x_t
            float xp = 0.f;
            const int b = (lane & 15) * 4;
#pragma unroll
            for (int m = 0; m < 4; m++) xp += xw[m] * xbuf[b + m];
            const int sel = lane >> 4;
            acc0 += (sel == 0) ? xp : 0.0f;
            acc1 += (sel == 1) ? xp : 0.0f;
            acc2 += (sel == 2) ? xp : 0.0f;
            acc3 += (sel == 3) ? xp : 0.0f;
        }
        // ---- 3. DPP reduce (VALU pipe); lane 63 posts to gbuf ----
        acc0 = wave_sum64_lane63(acc0);
        acc1 = wave_sum64_lane63(acc1);
        acc2 = wave_sum64_lane63(acc2);
        acc3 = wave_sum64_lane63(acc3);
        if (lane == 63) {
            gbuf[q * 8 + joff + 0] = acc0;
            gbuf[q * 8 + joff + 1] = acc1;
            gbuf[q * 8 + joff + 2] = acc2;
            gbuf[q * 8 + joff + 3] = acc3;
        }
        __syncthreads();   // barrier 2: gbuf ready; orders hbuf(t) reads
                           // before hbuf(t+1) staging writes

        // ---- 4. elementwise cell update, replicated in every wave (lanes 0..7);
        //         wave 0 publishes (32B store) then lane 0 release+add ----
        if (lane < 8) {
            float iv = sigmoid_f(gbuf[0 * 8 + lane] + bias[0]);
            float fv = sigmoid_f(gbuf[1 * 8 + lane] + bias[1]);
            float gv = tanh_fast(gbuf[2 * 8 + lane] + bias[2]);
            float ov = sigmoid_f(gbuf[3 * 8 + lane] + bias[3]);
            cstate = fv * cstate + iv * gv;
            float hval = ov * tanh_fast(cstate);
            if (w == 0) {
                __hip_atomic_store(Hbits + slot_w * H_DIM + cu * 8 + lane,
                                   __float_as_uint(hval),
                                   __ATOMIC_RELAXED, __HIP_MEMORY_SCOPE_AGENT);
            }
        }
        if (tid == 0) {
            // order the wave's publish stores before the counter increment
            __builtin_amdgcn_fence(__ATOMIC_RELEASE, "agent");
            atomicAdd(myCnt, 1u);
        }
    }
}

// Final linear: out[o] = h_T . W_lin[o,:] + b_lin[o].  One wave per output.
// h_T lives in slot (T_STEPS & 1) == 0.
__global__ void final_linear(const float* __restrict__ hT,
                             const float* __restrict__ Wlin,
                             const float* __restrict__ blin,
                             float* __restrict__ out)
{
    int gw   = (blockIdx.x * blockDim.x + threadIdx.x) >> 6;
    int lane = threadIdx.x & 63;
    if (gw < O_DIM) {
        const float* wp = Wlin + (size_t)gw * H_DIM;
        float s = 0.f;
        for (int k = lane; k < H_DIM; k += 64)
            s += wp[k] * hT[k];
#pragma unroll
        for (int off = 32; off; off >>= 1) s += __shfl_xor(s, off, 64);
        if (lane == 0) out[gw] = s + blin[gw];
    }
}

extern "C" void kernel_launch(void* const* d_in, const int* in_sizes, int n_in,
                              void* d_out, int out_size, void* d_ws, size_t ws_size,
                              hipStream_t stream)
{
    const float* x    = (const float*)d_in[0];
    const float* Wih  = (const float*)d_in[1];
    const float* Whh  = (const float*)d_in[2];
    const float* bih  = (const float*)d_in[3];
    const float* bhh  = (const float*)d_in[4];
    const float* Wlin = (const float*)d_in[5];
    const float* blin = (const float*)d_in[6];
    float* out = (float*)d_out;

    unsigned int* Hbits = (unsigned int*)d_ws;

    hipLaunchKernelGGL(init_ws_kernel, dim3((2 * H_DIM + 255) / 256), dim3(256),
                       0, stream, Hbits);

    void* args[] = { (void*)&x, (void*)&Wih, (void*)&Whh, (void*)&bih, (void*)&bhh,
                     (void*)&Hbits };
    (void)hipLaunchCooperativeKernel(reinterpret_cast<void*>(lstm_persistent),
                                     dim3(NBLK), dim3(NTHR), args, 0, stream);

    // h_T is in slot (T_STEPS & 1) == 0
    hipLaunchKernelGGL(final_linear, dim3(32), dim3(256), 0, stream,
                       (const float*)Hbits, Wlin, blin, out);
}